// Round 1
// baseline (9049.205 us; speedup 1.0000x reference)
//
#include <hip/hip_runtime.h>
#include <math.h>

#define H 256
#define NIN 512
#define NHEADS 4
#define BM 32
#define KC 32
#define XS 260   // padded row stride (words) for x1/x2 tiles
#define AS 36    // padded row stride for A staging tile

__device__ __forceinline__ float4 ld4(const float* p){ return *reinterpret_cast<const float4*>(p); }
__device__ __forceinline__ float gelu_exact(float x){ return 0.5f*x*(1.0f+erff(x*0.7071067811865476f)); }

// 4x8 rank-1 update from scalars a0..a3 and Ws row kk
#define MICRO() do { \
    float4 w0_ = *reinterpret_cast<const float4*>(&Ws[kk][tx8]); \
    float4 w1_ = *reinterpret_cast<const float4*>(&Ws[kk][tx8+4]); \
    float w_[8] = {w0_.x,w0_.y,w0_.z,w0_.w,w1_.x,w1_.y,w1_.z,w1_.w}; \
    _Pragma("unroll") \
    for (int j_=0;j_<8;j_++){ \
        acc[0][j_] = fmaf(a0, w_[j_], acc[0][j_]); \
        acc[1][j_] = fmaf(a1, w_[j_], acc[1][j_]); \
        acc[2][j_] = fmaf(a2, w_[j_], acc[2][j_]); \
        acc[3][j_] = fmaf(a3, w_[j_], acc[3][j_]); \
    } \
} while(0)

#define ZERO_ACC() do { \
    _Pragma("unroll") \
    for (int i_=0;i_<4;i_++){ \
        _Pragma("unroll") \
        for (int j_=0;j_<8;j_++) acc[i_][j_]=0.f; \
    } \
} while(0)

#define STAGE_W(WPTR, KB) do { \
    const float* wp_ = &(WPTR)[(size_t)((KB)+sr)*H + wc]; \
    _Pragma("unroll") \
    for (int q_=0;q_<8;q_++) \
        *reinterpret_cast<float4*>(&Ws[sr][wc+q_*4]) = ld4(wp_+4*q_); \
} while(0)

// ---------------- K0: per-node edge ranges (center_id is sorted) ----------------
__global__ void k_ranges(const int* __restrict__ center, int* __restrict__ start, int E, int N)
{
    int n = blockIdx.x*blockDim.x + threadIdx.x;
    if (n > N) return;
    if (n == N){ start[N] = E; return; }
    int lo = 0, hi = E;
    while (lo < hi){ int mid = (lo+hi)>>1; if (center[mid] < n) lo = mid+1; else hi = mid; }
    start[n] = lo;
}

// ---------------- K1: bias MLP -> logits ----------------
__global__ void __launch_bounds__(256)
k_bias(const float* __restrict__ hV, const float* __restrict__ hE,
       const float* __restrict__ b1w, const float* __restrict__ b1b,
       const float* __restrict__ b2w, const float* __restrict__ b2b,
       const float* __restrict__ b3w, const float* __restrict__ b3b,
       const int* __restrict__ center, float* __restrict__ logits, int E)
{
    __shared__ float As[BM][AS];
    __shared__ float Ws[KC][H];
    __shared__ float x1[BM][XS];
    __shared__ float x2[BM][XS];

    const int tid = threadIdx.x;
    const int tx8 = (tid & 31) * 8;
    const int ty4 = (tid >> 5) * 4;
    const int e0  = blockIdx.x * BM;
    const int sr  = tid >> 3;      // staging row 0..31
    const int kq  = tid & 7;
    const int wc  = kq * 32;

    float acc[4][8];
    ZERO_ACC();

    // ---- layer1: K = 768, A = concat(hV[center], hE)
    for (int kb = 0; kb < H+NIN; kb += KC){
        {
            int ge = e0 + sr; if (ge >= E) ge = E-1;
            int k = kb + kq*4;
            float4 a4 = (k < H) ? ld4(&hV[(size_t)center[ge]*H + k])
                                : ld4(&hE[(size_t)ge*NIN + (k-H)]);
            *reinterpret_cast<float4*>(&As[sr][kq*4]) = a4;
        }
        STAGE_W(b1w, kb);
        __syncthreads();
        #pragma unroll 8
        for (int kk=0; kk<KC; kk++){
            float a0=As[ty4+0][kk], a1=As[ty4+1][kk], a2=As[ty4+2][kk], a3=As[ty4+3][kk];
            MICRO();
        }
        __syncthreads();
    }
    #pragma unroll
    for (int j=0;j<8;j++){
        float b = b1b[tx8+j];
        #pragma unroll
        for (int i=0;i<4;i++) x1[ty4+i][tx8+j] = fmaxf(acc[i][j]+b, 0.f);
    }
    __syncthreads();

    // ---- layer2: K = 256, A = x1
    ZERO_ACC();
    for (int kb=0; kb<H; kb+=KC){
        STAGE_W(b2w, kb);
        __syncthreads();
        #pragma unroll 8
        for (int kk=0; kk<KC; kk++){
            int k = kb+kk;
            float a0=x1[ty4+0][k], a1=x1[ty4+1][k], a2=x1[ty4+2][k], a3=x1[ty4+3][k];
            MICRO();
        }
        __syncthreads();
    }
    #pragma unroll
    for (int j=0;j<8;j++){
        float b = b2b[tx8+j];
        #pragma unroll
        for (int i=0;i<4;i++) x2[ty4+i][tx8+j] = fmaxf(acc[i][j]+b, 0.f);
    }
    __syncthreads();

    // ---- layer3: 256 -> 4 ; logits = (x2 @ b3w + b3b)/8
    reinterpret_cast<float4*>(&Ws[0][0])[tid] = reinterpret_cast<const float4*>(b3w)[tid]; // 1024 floats
    __syncthreads();
    if (tid < BM*NHEADS){
        int e = tid >> 2, hh = tid & 3;
        const float* wsf = &Ws[0][0];
        float s = b3b[hh];
        #pragma unroll 8
        for (int k=0;k<H;k++) s = fmaf(x2[e][k], wsf[k*4+hh], s);
        int ge = e0 + e;
        if (ge < E) logits[(size_t)ge*NHEADS + hh] = s * 0.125f;
    }
}

// ---------------- K2: per-node softmax stats (max, sum of exp) ----------------
__global__ void k_smstats(const float* __restrict__ logits, const int* __restrict__ start,
                          float* __restrict__ mbuf, float* __restrict__ dbuf)
{
    int n = blockIdx.x;
    int s = start[n], e_end = start[n+1];
    int lane = threadIdx.x;
    int i = lane >> 2, hh = lane & 3;
    float mx = -INFINITY;
    for (int b = s + i; b < e_end; b += 16) mx = fmaxf(mx, logits[(size_t)b*NHEADS + hh]);
    #pragma unroll
    for (int off=4; off<64; off<<=1) mx = fmaxf(mx, __shfl_xor(mx, off, 64));
    float sum = 0.f;
    for (int b = s + i; b < e_end; b += 16) sum += expf(logits[(size_t)b*NHEADS + hh] - mx);
    #pragma unroll
    for (int off=4; off<64; off<<=1) sum += __shfl_xor(sum, off, 64);
    if (lane < 4){ mbuf[(size_t)n*NHEADS + hh] = mx; dbuf[(size_t)n*NHEADS + hh] = sum; }
}

// ---------------- K3: value MLP + attend + segmented scatter-add ----------------
__global__ void __launch_bounds__(256)
k_wv(const float* __restrict__ hE,
     const float* __restrict__ w1, const float* __restrict__ b1,
     const float* __restrict__ w2, const float* __restrict__ b2,
     const float* __restrict__ w3, const float* __restrict__ b3,
     const int* __restrict__ center, const float* __restrict__ logits,
     const float* __restrict__ mbuf, const float* __restrict__ dbuf,
     float* __restrict__ pre, int E)
{
    __shared__ float As[BM][AS];
    __shared__ float Ws[KC][H];
    __shared__ float x1[BM][XS];
    __shared__ float x2[BM][XS];
    __shared__ int   csh[BM];

    const int tid = threadIdx.x;
    const int tx8 = (tid & 31) * 8;
    const int ty4 = (tid >> 5) * 4;
    const int e0  = blockIdx.x * BM;
    const int sr  = tid >> 3;
    const int kq  = tid & 7;
    const int wc  = kq * 32;

    if (tid < BM){ int ge = e0 + tid; csh[tid] = center[ge < E ? ge : E-1]; }

    float acc[4][8];
    ZERO_ACC();

    // ---- layer1: K = 512, A = hE
    for (int kb=0; kb<NIN; kb+=KC){
        {
            int ge = e0 + sr; if (ge >= E) ge = E-1;
            int k = kb + kq*4;
            *reinterpret_cast<float4*>(&As[sr][kq*4]) = ld4(&hE[(size_t)ge*NIN + k]);
        }
        STAGE_W(w1, kb);
        __syncthreads();
        #pragma unroll 8
        for (int kk=0; kk<KC; kk++){
            float a0=As[ty4+0][kk], a1=As[ty4+1][kk], a2=As[ty4+2][kk], a3=As[ty4+3][kk];
            MICRO();
        }
        __syncthreads();
    }
    #pragma unroll
    for (int j=0;j<8;j++){
        float b = b1[tx8+j];
        #pragma unroll
        for (int i=0;i<4;i++) x1[ty4+i][tx8+j] = gelu_exact(acc[i][j]+b);
    }
    __syncthreads();

    // ---- layer2: K = 256, A = x1
    ZERO_ACC();
    for (int kb=0; kb<H; kb+=KC){
        STAGE_W(w2, kb);
        __syncthreads();
        #pragma unroll 8
        for (int kk=0; kk<KC; kk++){
            int k = kb+kk;
            float a0=x1[ty4+0][k], a1=x1[ty4+1][k], a2=x1[ty4+2][k], a3=x1[ty4+3][k];
            MICRO();
        }
        __syncthreads();
    }
    #pragma unroll
    for (int j=0;j<8;j++){
        float b = b2[tx8+j];
        #pragma unroll
        for (int i=0;i<4;i++) x2[ty4+i][tx8+j] = gelu_exact(acc[i][j]+b);
    }
    __syncthreads();

    // ---- layer3: K = 256, A = x2 (no activation)
    ZERO_ACC();
    for (int kb=0; kb<H; kb+=KC){
        STAGE_W(w3, kb);
        __syncthreads();
        #pragma unroll 8
        for (int kk=0; kk<KC; kk++){
            int k = kb+kk;
            float a0=x2[ty4+0][k], a1=x2[ty4+1][k], a2=x2[ty4+2][k], a3=x2[ty4+3][k];
            MICRO();
        }
        __syncthreads();
    }

    // ---- epilogue: attend weight + in-tile segmented column reduce
    const int hh = (tid & 31) >> 3;   // head for this thread's 8 output cols
    float att[4];
    #pragma unroll
    for (int i=0;i<4;i++){
        int e = ty4 + i;
        int ge = e0 + e; if (ge >= E) ge = E-1;
        int c = csh[e];
        att[i] = expf(logits[(size_t)ge*NHEADS + hh] - mbuf[(size_t)c*NHEADS + hh])
                 / dbuf[(size_t)c*NHEADS + hh];
    }
    #pragma unroll
    for (int j=0;j<8;j++){
        float b = b3[tx8+j];
        #pragma unroll
        for (int i=0;i<4;i++)
            x1[ty4+i][tx8+j] = (acc[i][j]+b) * att[i];
    }
    __syncthreads();
    {
        int col = tid;             // 256 threads == 256 columns
        float s = 0.f; int cur = csh[0];
        for (int e=0;e<BM;e++){
            if (e0 + e >= E) break;
            int c = csh[e];
            if (c != cur){ atomicAdd(&pre[(size_t)cur*H + col], s); s = 0.f; cur = c; }
            s += x1[e][col];
        }
        atomicAdd(&pre[(size_t)cur*H + col], s);
    }
}

// ---------------- K4: out = pre @ wo ----------------
__global__ void __launch_bounds__(256)
k_out(const float* __restrict__ pre, const float* __restrict__ wo,
      float* __restrict__ out, int N)
{
    __shared__ float ps[8][H];
    const int tid = threadIdx.x;
    const int nb = blockIdx.x * 8;
    {
        int r = tid >> 5, c = (tid & 31) * 8;
        if (nb + r < N){
            *reinterpret_cast<float4*>(&ps[r][c])   = ld4(&pre[(size_t)(nb+r)*H + c]);
            *reinterpret_cast<float4*>(&ps[r][c+4]) = ld4(&pre[(size_t)(nb+r)*H + c+4]);
        } else {
            #pragma unroll
            for (int q=0;q<8;q++) ps[r][c+q] = 0.f;
        }
    }
    __syncthreads();
    float a[8];
    #pragma unroll
    for (int i=0;i<8;i++) a[i]=0.f;
    #pragma unroll 4
    for (int k=0;k<H;k++){
        float w = wo[(size_t)k*H + tid];
        #pragma unroll
        for (int i=0;i<8;i++) a[i] = fmaf(ps[i][k], w, a[i]);
    }
    #pragma unroll
    for (int i=0;i<8;i++)
        if (nb + i < N) out[(size_t)(nb+i)*H + tid] = a[i];
}

extern "C" void kernel_launch(void* const* d_in, const int* in_sizes, int n_in,
                              void* d_out, int out_size, void* d_ws, size_t ws_size,
                              hipStream_t stream)
{
    const float* hV   = (const float*)d_in[0];
    const float* hE   = (const float*)d_in[1];
    const float* wv1w = (const float*)d_in[2];
    const float* wv1b = (const float*)d_in[3];
    const float* wv2w = (const float*)d_in[4];
    const float* wv2b = (const float*)d_in[5];
    const float* wv3w = (const float*)d_in[6];
    const float* wv3b = (const float*)d_in[7];
    const float* b1w  = (const float*)d_in[8];
    const float* b1b  = (const float*)d_in[9];
    const float* b2w  = (const float*)d_in[10];
    const float* b2b  = (const float*)d_in[11];
    const float* b3w  = (const float*)d_in[12];
    const float* b3b  = (const float*)d_in[13];
    const float* wow  = (const float*)d_in[14];
    const int*   center = (const int*)d_in[15];

    const int E = in_sizes[15];
    const int N = in_sizes[0] / H;

    float* pre    = (float*)d_ws;                    // N*H
    float* logits = pre + (size_t)N*H;               // E*NHEADS
    float* mbuf   = logits + (size_t)E*NHEADS;       // N*NHEADS
    float* dbuf   = mbuf + (size_t)N*NHEADS;         // N*NHEADS
    int*   start  = (int*)(dbuf + (size_t)N*NHEADS); // N+1

    hipMemsetAsync(pre, 0, (size_t)N*H*sizeof(float), stream);
    k_ranges<<<(N+1+255)/256, 256, 0, stream>>>(center, start, E, N);
    k_bias<<<(E+BM-1)/BM, 256, 0, stream>>>(hV,hE,b1w,b1b,b2w,b2b,b3w,b3b,center,logits,E);
    k_smstats<<<N, 64, 0, stream>>>(logits, start, mbuf, dbuf);
    k_wv<<<(E+BM-1)/BM, 256, 0, stream>>>(hE,wv1w,wv1b,wv2w,wv2b,wv3w,wv3b,center,logits,mbuf,dbuf,pre,E);
    k_out<<<(N+7)/8, 256, 0, stream>>>(pre, wow, (float*)d_out, N);
}

// Round 2
// 1278.368 us; speedup vs baseline: 7.0787x; 7.0787x over previous
//
#include <hip/hip_runtime.h>
#include <math.h>

#define H 256
#define NIN 512
#define NHEADS 4
#define BM 32

typedef __attribute__((ext_vector_type(8))) short short8;
typedef __attribute__((ext_vector_type(4))) short short4v;
typedef __attribute__((ext_vector_type(4))) float floatx4;

__device__ __forceinline__ float4 ld4(const float* p){ return *reinterpret_cast<const float4*>(p); }

__device__ __forceinline__ short f2bf(float x){   // RNE f32->bf16
    unsigned u = __float_as_uint(x);
    u += 0x7FFF + ((u >> 16) & 1);
    return (short)(u >> 16);
}
__device__ __forceinline__ float bf2f(short h){
    return __uint_as_float(((unsigned)(unsigned short)h) << 16);
}
__device__ __forceinline__ float gelu_exact(float x){ return 0.5f*x*(1.0f+erff(x*0.7071067811865476f)); }

__device__ __forceinline__ floatx4 mfma16(short8 a, short8 b, floatx4 c){
    return __builtin_amdgcn_mfma_f32_16x16x32_bf16(a, b, c, 0, 0, 0);
}
__device__ __forceinline__ short8 pack8(float4 a, float4 b){
    short8 v;
    v[0]=f2bf(a.x); v[1]=f2bf(a.y); v[2]=f2bf(a.z); v[3]=f2bf(a.w);
    v[4]=f2bf(b.x); v[5]=f2bf(b.y); v[6]=f2bf(b.z); v[7]=f2bf(b.w);
    return v;
}

// ---------------- K0: per-node edge ranges (center_id sorted) ----------------
__global__ void k_ranges(const int* __restrict__ center, int* __restrict__ start, int E, int N)
{
    int n = blockIdx.x*blockDim.x + threadIdx.x;
    if (n > N) return;
    if (n == N){ start[N] = E; return; }
    int lo = 0, hi = E;
    while (lo < hi){ int mid = (lo+hi)>>1; if (center[mid] < n) lo = mid+1; else hi = mid; }
    start[n] = lo;
}

// ------------- weight convert+transpose: dst[c][k] = bf16(src[k][c]), src [K][256] -------------
__global__ void __launch_bounds__(256)
k_wconv(const float* __restrict__ src, short* __restrict__ dst, int K)
{
    __shared__ float t[32][33];
    const int k0 = blockIdx.x*32, c0 = blockIdx.y*32;
    const int tid = threadIdx.x;
    const int r = tid >> 3, q = tid & 7;
    float4 v = ld4(&src[(size_t)(k0 + r)*H + c0 + q*4]);
    t[r][q*4+0] = v.x; t[r][q*4+1] = v.y; t[r][q*4+2] = v.z; t[r][q*4+3] = v.w;
    __syncthreads();
    short4v o;
    o[0]=f2bf(t[q*4+0][r]); o[1]=f2bf(t[q*4+1][r]); o[2]=f2bf(t[q*4+2][r]); o[3]=f2bf(t[q*4+3][r]);
    *reinterpret_cast<short4v*>(&dst[(size_t)(c0 + r)*K + k0 + q*4]) = o;
}

// ------------- nodebias[n][j] = hV[n]@b1w[:256,j] + b1b[j]  (f32 VALU) -------------
__global__ void __launch_bounds__(256)
k_nodebias(const float* __restrict__ hV, const float* __restrict__ b1w,
           const float* __restrict__ b1b, float* __restrict__ nb, int N)
{
    __shared__ float ps[8][260];
    const int n0 = blockIdx.x*8;
    const int tid = threadIdx.x;
    {
        int r = tid >> 5, cq = (tid & 31)*8;
        *reinterpret_cast<float4*>(&ps[r][cq])   = ld4(&hV[(size_t)(n0+r)*H + cq]);
        *reinterpret_cast<float4*>(&ps[r][cq+4]) = ld4(&hV[(size_t)(n0+r)*H + cq + 4]);
    }
    __syncthreads();
    float a[8];
    float bias = b1b[tid];
    #pragma unroll
    for (int i=0;i<8;i++) a[i] = bias;
    #pragma unroll 4
    for (int k=0;k<H;k++){
        float w = b1w[(size_t)k*H + tid];
        #pragma unroll
        for (int i=0;i<8;i++) a[i] = fmaf(ps[i][k], w, a[i]);
    }
    #pragma unroll
    for (int i=0;i<8;i++) nb[(size_t)(n0+i)*H + tid] = a[i];
}

// ---------------- K1: bias MLP (bf16 MFMA) -> logits ----------------
__global__ void __launch_bounds__(256,2)
k_bias2(const float* __restrict__ hE,
        const short* __restrict__ Wt1,      // [256][512]
        const short* __restrict__ Wt2,      // [256][256]
        const float* __restrict__ b3w,      // [256][4] f32
        const float* __restrict__ b3b,      // [4]
        const float* __restrict__ b2b,      // [256]
        const float* __restrict__ nodebias, // [N][256] (includes b1b)
        const int* __restrict__ center,
        float* __restrict__ logits, int E)
{
    __shared__ short Alds[2][BM][72];
    __shared__ short xarena[2][BM][264];
    __shared__ int   csh[BM];

    const int tid = threadIdx.x;
    const int lane = tid & 63, w = tid >> 6;
    const int lr = lane & 15, lh = lane >> 4;
    const int e0 = blockIdx.x * BM;
    const int c0 = w * 64;
    const int srow = tid >> 3, skq = tid & 7;
    const float* aSrc = hE + (size_t)(e0 + srow) * NIN + skq * 8;

    if (tid < BM) csh[tid] = center[e0 + tid];

    float4 pf0 = ld4(aSrc), pf1 = ld4(aSrc + 4);
    *reinterpret_cast<short8*>(&Alds[0][srow][skq*8]) = pack8(pf0, pf1);
    __syncthreads();

    floatx4 acc[2][4];
    #pragma unroll
    for (int rb=0;rb<2;rb++)
        #pragma unroll
        for (int n=0;n<4;n++) acc[rb][n] = (floatx4){0.f,0.f,0.f,0.f};

    // ---- layer1: K=512, A = hE (staged), C += nodebias later
    for (int ch = 0; ch < 8; ch++){
        const int buf = ch & 1;
        if (ch < 7){ pf0 = ld4(aSrc + (ch+1)*64); pf1 = ld4(aSrc + (ch+1)*64 + 4); }
        short8 bfr[2][4], af[2][2];
        #pragma unroll
        for (int s=0;s<2;s++){
            #pragma unroll
            for (int n=0;n<4;n++)
                bfr[s][n] = *reinterpret_cast<const short8*>(
                    &Wt1[(size_t)(c0 + n*16 + lr)*NIN + ch*64 + s*32 + lh*8]);
            #pragma unroll
            for (int rb=0;rb<2;rb++)
                af[s][rb] = *reinterpret_cast<const short8*>(&Alds[buf][rb*16+lr][s*32+lh*8]);
        }
        #pragma unroll
        for (int s=0;s<2;s++)
            #pragma unroll
            for (int n=0;n<4;n++)
                #pragma unroll
                for (int rb=0;rb<2;rb++)
                    acc[rb][n] = mfma16(af[s][rb], bfr[s][n], acc[rb][n]);
        if (ch < 7)
            *reinterpret_cast<short8*>(&Alds[buf^1][srow][skq*8]) = pack8(pf0, pf1);
        __syncthreads();
    }
    // epilogue1: + nodebias[center], ReLU, -> xa (bf16)
    #pragma unroll
    for (int rb=0;rb<2;rb++)
        #pragma unroll
        for (int j=0;j<4;j++){
            const int row = rb*16 + lh*4 + j;
            const int c = csh[row];
            const float* nb = nodebias + (size_t)c*H + c0 + lr;
            #pragma unroll
            for (int n=0;n<4;n++){
                float v = acc[rb][n][j] + nb[n*16];
                xarena[0][row][c0 + n*16 + lr] = f2bf(fmaxf(v, 0.f));
            }
        }
    __syncthreads();

    // stage padded W3^T (16 cols x 256 k) into Alds area (free after layer1)
    {
        short* w3s = &Alds[0][0][0];   // [16][264]
        #pragma unroll
        for (int c=0;c<4;c++)  w3s[c*264 + tid] = f2bf(b3w[(size_t)tid*NHEADS + c]);
        #pragma unroll
        for (int c=4;c<16;c++) w3s[c*264 + tid] = 0;
    }

    // ---- layer2: K=256, A = xa
    float bb[4];
    #pragma unroll
    for (int n=0;n<4;n++) bb[n] = b2b[c0 + n*16 + lr];
    #pragma unroll
    for (int rb=0;rb<2;rb++)
        #pragma unroll
        for (int n=0;n<4;n++) acc[rb][n] = (floatx4){0.f,0.f,0.f,0.f};
    for (int ch = 0; ch < 4; ch++){
        short8 bfr[2][4], af[2][2];
        #pragma unroll
        for (int s=0;s<2;s++){
            #pragma unroll
            for (int n=0;n<4;n++)
                bfr[s][n] = *reinterpret_cast<const short8*>(
                    &Wt2[(size_t)(c0 + n*16 + lr)*H + ch*64 + s*32 + lh*8]);
            #pragma unroll
            for (int rb=0;rb<2;rb++)
                af[s][rb] = *reinterpret_cast<const short8*>(&xarena[0][rb*16+lr][ch*64+s*32+lh*8]);
        }
        #pragma unroll
        for (int s=0;s<2;s++)
            #pragma unroll
            for (int n=0;n<4;n++)
                #pragma unroll
                for (int rb=0;rb<2;rb++)
                    acc[rb][n] = mfma16(af[s][rb], bfr[s][n], acc[rb][n]);
    }
    // epilogue2: + b2b, ReLU -> xb
    #pragma unroll
    for (int rb=0;rb<2;rb++)
        #pragma unroll
        for (int j=0;j<4;j++){
            const int row = rb*16 + lh*4 + j;
            #pragma unroll
            for (int n=0;n<4;n++)
                xarena[1][row][c0 + n*16 + lr] = f2bf(fmaxf(acc[rb][n][j] + bb[n], 0.f));
        }
    __syncthreads();

    // ---- layer3: K=256, N=4 (padded to 16). All waves compute redundantly; wave 0 writes.
    {
        const short* w3s = &Alds[0][0][0];
        floatx4 a3[2];
        a3[0] = (floatx4){0.f,0.f,0.f,0.f}; a3[1] = (floatx4){0.f,0.f,0.f,0.f};
        for (int ch = 0; ch < 4; ch++){
            #pragma unroll
            for (int s=0;s<2;s++){
                short8 bfr = *reinterpret_cast<const short8*>(&w3s[lr*264 + ch*64 + s*32 + lh*8]);
                #pragma unroll
                for (int rb=0;rb<2;rb++){
                    short8 af = *reinterpret_cast<const short8*>(&xarena[1][rb*16+lr][ch*64+s*32+lh*8]);
                    a3[rb] = mfma16(af, bfr, a3[rb]);
                }
            }
        }
        if (w == 0 && lr < NHEADS){
            float bias = b3b[lr];
            #pragma unroll
            for (int rb=0;rb<2;rb++)
                #pragma unroll
                for (int j=0;j<4;j++){
                    int row = rb*16 + lh*4 + j;
                    logits[(size_t)(e0+row)*NHEADS + lr] = (a3[rb][j] + bias) * 0.125f;
                }
        }
    }
}

// ---------------- K2: per-node softmax stats ----------------
__global__ void k_smstats(const float* __restrict__ logits, const int* __restrict__ start,
                          float* __restrict__ mbuf, float* __restrict__ dbuf)
{
    int n = blockIdx.x;
    int s = start[n], e_end = start[n+1];
    int lane = threadIdx.x;
    int i = lane >> 2, hh = lane & 3;
    float mx = -INFINITY;
    for (int b = s + i; b < e_end; b += 16) mx = fmaxf(mx, logits[(size_t)b*NHEADS + hh]);
    #pragma unroll
    for (int off=4; off<64; off<<=1) mx = fmaxf(mx, __shfl_xor(mx, off, 64));
    float sum = 0.f;
    for (int b = s + i; b < e_end; b += 16) sum += expf(logits[(size_t)b*NHEADS + hh] - mx);
    #pragma unroll
    for (int off=4; off<64; off<<=1) sum += __shfl_xor(sum, off, 64);
    if (lane < 4){ mbuf[(size_t)n*NHEADS + hh] = mx; dbuf[(size_t)n*NHEADS + hh] = sum; }
}

// ---------------- K3: value MLP (bf16 MFMA) + attend + segmented scatter-add ----------------
__global__ void __launch_bounds__(256,2)
k_wv2(const float* __restrict__ hE,
      const short* __restrict__ Wt1, const float* __restrict__ b1v,
      const short* __restrict__ Wt2, const float* __restrict__ b2v,
      const short* __restrict__ Wt3, const float* __restrict__ b3v,
      const int* __restrict__ center, const float* __restrict__ logits,
      const float* __restrict__ mbuf, const float* __restrict__ dbuf,
      float* __restrict__ pre, int E)
{
    __shared__ short Alds[2][BM][72];
    __shared__ short xarena[2][BM][264];
    __shared__ int   csh[BM];

    const int tid = threadIdx.x;
    const int lane = tid & 63, w = tid >> 6;
    const int lr = lane & 15, lh = lane >> 4;
    const int e0 = blockIdx.x * BM;
    const int c0 = w * 64;
    const int srow = tid >> 3, skq = tid & 7;
    const float* aSrc = hE + (size_t)(e0 + srow) * NIN + skq * 8;

    if (tid < BM) csh[tid] = center[e0 + tid];

    float4 pf0 = ld4(aSrc), pf1 = ld4(aSrc + 4);
    *reinterpret_cast<short8*>(&Alds[0][srow][skq*8]) = pack8(pf0, pf1);
    __syncthreads();

    floatx4 acc[2][4];
    #pragma unroll
    for (int rb=0;rb<2;rb++)
        #pragma unroll
        for (int n=0;n<4;n++) acc[rb][n] = (floatx4){0.f,0.f,0.f,0.f};

    // ---- layer1: K=512
    for (int ch = 0; ch < 8; ch++){
        const int buf = ch & 1;
        if (ch < 7){ pf0 = ld4(aSrc + (ch+1)*64); pf1 = ld4(aSrc + (ch+1)*64 + 4); }
        short8 bfr[2][4], af[2][2];
        #pragma unroll
        for (int s=0;s<2;s++){
            #pragma unroll
            for (int n=0;n<4;n++)
                bfr[s][n] = *reinterpret_cast<const short8*>(
                    &Wt1[(size_t)(c0 + n*16 + lr)*NIN + ch*64 + s*32 + lh*8]);
            #pragma unroll
            for (int rb=0;rb<2;rb++)
                af[s][rb] = *reinterpret_cast<const short8*>(&Alds[buf][rb*16+lr][s*32+lh*8]);
        }
        #pragma unroll
        for (int s=0;s<2;s++)
            #pragma unroll
            for (int n=0;n<4;n++)
                #pragma unroll
                for (int rb=0;rb<2;rb++)
                    acc[rb][n] = mfma16(af[s][rb], bfr[s][n], acc[rb][n]);
        if (ch < 7)
            *reinterpret_cast<short8*>(&Alds[buf^1][srow][skq*8]) = pack8(pf0, pf1);
        __syncthreads();
    }
    {
        float bc[4];
        #pragma unroll
        for (int n=0;n<4;n++) bc[n] = b1v[c0 + n*16 + lr];
        #pragma unroll
        for (int rb=0;rb<2;rb++)
            #pragma unroll
            for (int j=0;j<4;j++){
                const int row = rb*16 + lh*4 + j;
                #pragma unroll
                for (int n=0;n<4;n++)
                    xarena[0][row][c0 + n*16 + lr] = f2bf(gelu_exact(acc[rb][n][j] + bc[n]));
            }
    }
    __syncthreads();

    // ---- layer2: K=256
    float bc2[4];
    #pragma unroll
    for (int n=0;n<4;n++) bc2[n] = b2v[c0 + n*16 + lr];
    #pragma unroll
    for (int rb=0;rb<2;rb++)
        #pragma unroll
        for (int n=0;n<4;n++) acc[rb][n] = (floatx4){0.f,0.f,0.f,0.f};
    for (int ch = 0; ch < 4; ch++){
        short8 bfr[2][4], af[2][2];
        #pragma unroll
        for (int s=0;s<2;s++){
            #pragma unroll
            for (int n=0;n<4;n++)
                bfr[s][n] = *reinterpret_cast<const short8*>(
                    &Wt2[(size_t)(c0 + n*16 + lr)*H + ch*64 + s*32 + lh*8]);
            #pragma unroll
            for (int rb=0;rb<2;rb++)
                af[s][rb] = *reinterpret_cast<const short8*>(&xarena[0][rb*16+lr][ch*64+s*32+lh*8]);
        }
        #pragma unroll
        for (int s=0;s<2;s++)
            #pragma unroll
            for (int n=0;n<4;n++)
                #pragma unroll
                for (int rb=0;rb<2;rb++)
                    acc[rb][n] = mfma16(af[s][rb], bfr[s][n], acc[rb][n]);
    }
    #pragma unroll
    for (int rb=0;rb<2;rb++)
        #pragma unroll
        for (int j=0;j<4;j++){
            const int row = rb*16 + lh*4 + j;
            #pragma unroll
            for (int n=0;n<4;n++)
                xarena[1][row][c0 + n*16 + lr] = f2bf(gelu_exact(acc[rb][n][j] + bc2[n]));
        }
    __syncthreads();

    // ---- layer3: K=256 (no activation)
    float bc3[4];
    #pragma unroll
    for (int n=0;n<4;n++) bc3[n] = b3v[c0 + n*16 + lr];
    #pragma unroll
    for (int rb=0;rb<2;rb++)
        #pragma unroll
        for (int n=0;n<4;n++) acc[rb][n] = (floatx4){0.f,0.f,0.f,0.f};
    for (int ch = 0; ch < 4; ch++){
        short8 bfr[2][4], af[2][2];
        #pragma unroll
        for (int s=0;s<2;s++){
            #pragma unroll
            for (int n=0;n<4;n++)
                bfr[s][n] = *reinterpret_cast<const short8*>(
                    &Wt3[(size_t)(c0 + n*16 + lr)*H + ch*64 + s*32 + lh*8]);
            #pragma unroll
            for (int rb=0;rb<2;rb++)
                af[s][rb] = *reinterpret_cast<const short8*>(&xarena[1][rb*16+lr][ch*64+s*32+lh*8]);
        }
        #pragma unroll
        for (int s=0;s<2;s++)
            #pragma unroll
            for (int n=0;n<4;n++)
                #pragma unroll
                for (int rb=0;rb<2;rb++)
                    acc[rb][n] = mfma16(af[s][rb], bfr[s][n], acc[rb][n]);
    }
    __syncthreads();   // all xarena reads done before f32 overlay writes

    // ---- epilogue: attend (head == wave), f32 tile, segmented column reduce
    float* xf = reinterpret_cast<float*>(&xarena[0][0][0]);   // [32][264] f32
    #pragma unroll
    for (int rb=0;rb<2;rb++)
        #pragma unroll
        for (int j=0;j<4;j++){
            const int row = rb*16 + lh*4 + j;
            const int ge = e0 + row;
            const int c = csh[row];
            const float att = expf(logits[(size_t)ge*NHEADS + w] - mbuf[(size_t)c*NHEADS + w])
                              / dbuf[(size_t)c*NHEADS + w];
            #pragma unroll
            for (int n=0;n<4;n++)
                xf[row*264 + c0 + n*16 + lr] = (acc[rb][n][j] + bc3[n]) * att;
        }
    __syncthreads();
    {
        const int col = tid;
        float s = 0.f; int cur = csh[0];
        for (int e=0;e<BM;e++){
            int c = csh[e];
            if (c != cur){ atomicAdd(&pre[(size_t)cur*H + col], s); s = 0.f; cur = c; }
            s += xf[e*264 + col];
        }
        atomicAdd(&pre[(size_t)cur*H + col], s);
    }
}

// ---------------- K4: out = pre @ wo (f32) ----------------
__global__ void __launch_bounds__(256)
k_out(const float* __restrict__ pre, const float* __restrict__ wo,
      float* __restrict__ out, int N)
{
    __shared__ float ps[8][260];
    const int tid = threadIdx.x;
    const int nb = blockIdx.x * 8;
    {
        int r = tid >> 5, c = (tid & 31) * 8;
        *reinterpret_cast<float4*>(&ps[r][c])   = ld4(&pre[(size_t)(nb+r)*H + c]);
        *reinterpret_cast<float4*>(&ps[r][c+4]) = ld4(&pre[(size_t)(nb+r)*H + c+4]);
    }
    __syncthreads();
    float a[8];
    #pragma unroll
    for (int i=0;i<8;i++) a[i]=0.f;
    #pragma unroll 4
    for (int k=0;k<H;k++){
        float w = wo[(size_t)k*H + tid];
        #pragma unroll
        for (int i=0;i<8;i++) a[i] = fmaf(ps[i][k], w, a[i]);
    }
    #pragma unroll
    for (int i=0;i<8;i++)
        out[(size_t)(nb+i)*H + tid] = a[i];
}

extern "C" void kernel_launch(void* const* d_in, const int* in_sizes, int n_in,
                              void* d_out, int out_size, void* d_ws, size_t ws_size,
                              hipStream_t stream)
{
    const float* hV   = (const float*)d_in[0];
    const float* hE   = (const float*)d_in[1];
    const float* wv1w = (const float*)d_in[2];
    const float* wv1b = (const float*)d_in[3];
    const float* wv2w = (const float*)d_in[4];
    const float* wv2b = (const float*)d_in[5];
    const float* wv3w = (const float*)d_in[6];
    const float* wv3b = (const float*)d_in[7];
    const float* b1w  = (const float*)d_in[8];
    const float* b1b  = (const float*)d_in[9];
    const float* b2w  = (const float*)d_in[10];
    const float* b2b  = (const float*)d_in[11];
    const float* b3w  = (const float*)d_in[12];
    const float* b3b  = (const float*)d_in[13];
    const float* wow  = (const float*)d_in[14];
    const int*   center = (const int*)d_in[15];

    const int E = in_sizes[15];
    const int N = in_sizes[0] / H;

    float* pre      = (float*)d_ws;                       // N*H
    float* logits   = pre + (size_t)N*H;                  // E*4
    float* mbuf     = logits + (size_t)E*NHEADS;          // N*4
    float* dbuf     = mbuf + (size_t)N*NHEADS;            // N*4
    int*   start    = (int*)(dbuf + (size_t)N*NHEADS);    // N+1 (padded to x4)
    float* nodebias = (float*)(start + ((N+1+3)&~3));     // N*H
    short* wt1b     = (short*)(nodebias + (size_t)N*H);   // 256*512
    short* wt2b     = wt1b + 256*512;                     // 256*256
    short* wt1v     = wt2b + 256*256;                     // 256*512
    short* wt2v     = wt1v + 256*512;                     // 256*256
    short* wt3v     = wt2v + 256*256;                     // 256*256

    hipMemsetAsync(pre, 0, (size_t)N*H*sizeof(float), stream);
    k_ranges<<<(N+1+255)/256, 256, 0, stream>>>(center, start, E, N);
    k_wconv<<<dim3(16,8), 256, 0, stream>>>(b1w + 256*H, wt1b, 512);
    k_wconv<<<dim3(8,8),  256, 0, stream>>>(b2w,  wt2b, 256);
    k_wconv<<<dim3(16,8), 256, 0, stream>>>(wv1w, wt1v, 512);
    k_wconv<<<dim3(8,8),  256, 0, stream>>>(wv2w, wt2v, 256);
    k_wconv<<<dim3(8,8),  256, 0, stream>>>(wv3w, wt3v, 256);
    k_nodebias<<<N/8, 256, 0, stream>>>(hV, b1w, b1b, nodebias, N);
    k_bias2<<<E/BM, 256, 0, stream>>>(hE, wt1b, wt2b, b3w, b3b, b2b, nodebias, center, logits, E);
    k_smstats<<<N, 64, 0, stream>>>(logits, start, mbuf, dbuf);
    k_wv2<<<E/BM, 256, 0, stream>>>(hE, wt1v, wv1b, wt2v, wv2b, wt3v, wv3b,
                                    center, logits, mbuf, dbuf, pre, E);
    k_out<<<N/8, 256, 0, stream>>>(pre, wow, (float*)d_out, N);
}

// Round 3
// 904.718 us; speedup vs baseline: 10.0022x; 1.4130x over previous
//
#include <hip/hip_runtime.h>
#include <hip/hip_bf16.h>
#include <math.h>

#define H 256
#define NIN 512
#define NHEADS 4
#define BM 64
#define LOG2E 1.4426950408889634f

typedef __attribute__((ext_vector_type(8))) short short8;
typedef __attribute__((ext_vector_type(4))) short short4v;
typedef __attribute__((ext_vector_type(4))) float floatx4;

__device__ __forceinline__ float4 ld4(const float* p){ return *reinterpret_cast<const float4*>(p); }

__device__ __forceinline__ short f2bf(float x){
    __hip_bfloat16 h = __float2bfloat16(x);
    return *reinterpret_cast<short*>(&h);
}
__device__ __forceinline__ float bf2f(short h){
    return __uint_as_float(((unsigned)(unsigned short)h) << 16);
}
__device__ __forceinline__ float fexp2(float x){ return __builtin_amdgcn_exp2f(x); }
__device__ __forceinline__ float frcp(float x){ return __builtin_amdgcn_rcpf(x); }

// tanh-form GELU with hw exp/rcp: max dev from exact ~1e-3
__device__ __forceinline__ float gelu_fast(float x){
    float y = x * fmaf(x*x, 0.0356774081f, 0.7978845608f);
    float t = fexp2(-2.8853900818f * fabsf(y));          // e^{-2|y|}
    float th = (1.f - t) * frcp(1.f + t);
    th = copysignf(th, y);
    return 0.5f * x * (1.f + th);
}
__device__ __forceinline__ floatx4 mfma16(short8 a, short8 b, floatx4 c){
    return __builtin_amdgcn_mfma_f32_16x16x32_bf16(a, b, c, 0, 0, 0);
}
__device__ __forceinline__ short8 pack8(float4 a, float4 b){
    short8 v;
    v[0]=f2bf(a.x); v[1]=f2bf(a.y); v[2]=f2bf(a.z); v[3]=f2bf(a.w);
    v[4]=f2bf(b.x); v[5]=f2bf(b.y); v[6]=f2bf(b.z); v[7]=f2bf(b.w);
    return v;
}

#define ZERO_ACC() do { \
    _Pragma("unroll") \
    for (int i_=0;i_<4;i_++){ \
        _Pragma("unroll") \
        for (int j_=0;j_<4;j_++) acc[i_][j_] = (floatx4){0.f,0.f,0.f,0.f}; \
    } \
} while(0)

// one K=64 chunk: A from (ABASE, stride ASTR shorts, col offset AOFF), B from WPTR (row-stride KW)
#define MFMA_CH(ABASE, ASTR, AOFF, WPTR, KW, KOFF) do { \
    _Pragma("unroll") \
    for (int s_=0;s_<2;s_++){ \
        short8 bfr_[4]; \
        _Pragma("unroll") \
        for (int n_=0;n_<4;n_++) \
            bfr_[n_] = *reinterpret_cast<const short8*>( \
                &(WPTR)[(size_t)(c0 + n_*16 + lr)*(KW) + (KOFF) + s_*32 + lh*8]); \
        short8 af_[4]; \
        _Pragma("unroll") \
        for (int rb_=0;rb_<4;rb_++) \
            af_[rb_] = *reinterpret_cast<const short8*>( \
                &(ABASE)[(rb_*16+lr)*(ASTR) + (AOFF) + s_*32 + lh*8]); \
        _Pragma("unroll") \
        for (int n_=0;n_<4;n_++) \
            _Pragma("unroll") \
            for (int rb_=0;rb_<4;rb_++) \
                acc[rb_][n_] = mfma16(af_[rb_], bfr_[n_], acc[rb_][n_]); \
    } \
} while(0)

// ---------------- K0: per-node edge ranges (center_id sorted) ----------------
__global__ void k_ranges(const int* __restrict__ center, int* __restrict__ start, int E, int N)
{
    int n = blockIdx.x*blockDim.x + threadIdx.x;
    if (n > N) return;
    if (n == N){ start[N] = E; return; }
    int lo = 0, hi = E;
    while (lo < hi){ int mid = (lo+hi)>>1; if (center[mid] < n) lo = mid+1; else hi = mid; }
    start[n] = lo;
}

// ------------- weight convert+transpose: dst[c][k] = bf16(src[k][c]), src [K][256] -------------
__global__ void __launch_bounds__(256)
k_wconv(const float* __restrict__ src, short* __restrict__ dst, int K)
{
    __shared__ float t[32][33];
    const int k0 = blockIdx.x*32, c0 = blockIdx.y*32;
    const int tid = threadIdx.x;
    const int r = tid >> 3, q = tid & 7;
    float4 v = ld4(&src[(size_t)(k0 + r)*H + c0 + q*4]);
    t[r][q*4+0] = v.x; t[r][q*4+1] = v.y; t[r][q*4+2] = v.z; t[r][q*4+3] = v.w;
    __syncthreads();
    short4v o;
    o[0]=f2bf(t[q*4+0][r]); o[1]=f2bf(t[q*4+1][r]); o[2]=f2bf(t[q*4+2][r]); o[3]=f2bf(t[q*4+3][r]);
    *reinterpret_cast<short4v*>(&dst[(size_t)(c0 + r)*K + k0 + q*4]) = o;
}

// ------------- pad bias-W3 to [16][256] bf16 (cols 4..15 zero) -------------
__global__ void k_w3pad(const float* __restrict__ b3w, short* __restrict__ dst)
{
    const int k = threadIdx.x;
    #pragma unroll
    for (int c=0;c<16;c++)
        dst[c*H + k] = (c < NHEADS) ? f2bf(b3w[(size_t)k*NHEADS + c]) : (short)0;
}

// ------------- nodebias[n][j] = hV[n]@b1w[:256,j] + b1b[j]  (f32 VALU) -------------
__global__ void __launch_bounds__(256)
k_nodebias(const float* __restrict__ hV, const float* __restrict__ b1w,
           const float* __restrict__ b1b, float* __restrict__ nb, int N)
{
    __shared__ float ps[8][260];
    const int n0 = blockIdx.x*8;
    const int tid = threadIdx.x;
    {
        int r = tid >> 5, cq = (tid & 31)*8;
        *reinterpret_cast<float4*>(&ps[r][cq])   = ld4(&hV[(size_t)(n0+r)*H + cq]);
        *reinterpret_cast<float4*>(&ps[r][cq+4]) = ld4(&hV[(size_t)(n0+r)*H + cq + 4]);
    }
    __syncthreads();
    float a[8];
    float bias = b1b[tid];
    #pragma unroll
    for (int i=0;i<8;i++) a[i] = bias;
    #pragma unroll 4
    for (int k=0;k<H;k++){
        float w = b1w[(size_t)k*H + tid];
        #pragma unroll
        for (int i=0;i<8;i++) a[i] = fmaf(ps[i][k], w, a[i]);
    }
    #pragma unroll
    for (int i=0;i<8;i++) nb[(size_t)(n0+i)*H + tid] = a[i];
}

// ---------------- K1: bias MLP (bf16 MFMA, BM=64) -> logits ----------------
__global__ void __launch_bounds__(256,3)
k_bias2(const float* __restrict__ hE,
        const short* __restrict__ Wt1,      // [256][512]
        const short* __restrict__ Wt2,      // [256][256]
        const short* __restrict__ W3p,      // [16][256] padded
        const float* __restrict__ b3b,
        const float* __restrict__ b2b,
        const float* __restrict__ nodebias, // [N][256] (includes b1b)
        const int* __restrict__ center,
        float* __restrict__ logits, int E)
{
    __shared__ short Alds[2][BM][72];
    __shared__ short xarena[BM][264];
    __shared__ int   csh[BM];

    const int tid = threadIdx.x;
    const int lane = tid & 63, w = tid >> 6;
    const int lr = lane & 15, lh = lane >> 4;
    const int e0 = blockIdx.x * BM;
    const int c0 = w * 64;
    const int srow = tid >> 2, skq = tid & 3;
    const int gsrow = (e0 + srow < E) ? (e0 + srow) : (E-1);
    const float* aSrc = hE + (size_t)gsrow * NIN + skq * 16;

    if (tid < BM){ int ge = e0 + tid; csh[tid] = center[ge < E ? ge : E-1]; }

    float4 pf[4];
    #pragma unroll
    for (int q=0;q<4;q++) pf[q] = ld4(aSrc + q*4);
    *reinterpret_cast<short8*>(&Alds[0][srow][skq*16])   = pack8(pf[0], pf[1]);
    *reinterpret_cast<short8*>(&Alds[0][srow][skq*16+8]) = pack8(pf[2], pf[3]);

    floatx4 acc[4][4];
    ZERO_ACC();

    // ---- layer1: K=512
    for (int ch = 0; ch < 8; ch++){
        __syncthreads();
        if (ch < 7){
            #pragma unroll
            for (int q=0;q<4;q++) pf[q] = ld4(aSrc + (ch+1)*64 + q*4);
        }
        MFMA_CH(&Alds[ch&1][0][0], 72, 0, Wt1, NIN, ch*64);
        if (ch < 7){
            *reinterpret_cast<short8*>(&Alds[(ch&1)^1][srow][skq*16])   = pack8(pf[0], pf[1]);
            *reinterpret_cast<short8*>(&Alds[(ch&1)^1][srow][skq*16+8]) = pack8(pf[2], pf[3]);
        }
    }
    // epilogue1: + nodebias[center], ReLU -> xarena bf16
    #pragma unroll
    for (int rb=0;rb<4;rb++)
        #pragma unroll
        for (int j=0;j<4;j++){
            const int row = rb*16 + lh*4 + j;
            const float* nb = nodebias + (size_t)csh[row]*H + c0 + lr;
            #pragma unroll
            for (int n=0;n<4;n++)
                xarena[row][c0 + n*16 + lr] = f2bf(fmaxf(acc[rb][n][j] + nb[n*16], 0.f));
        }
    __syncthreads();

    // ---- layer2: K=256 (read all, then overwrite)
    ZERO_ACC();
    for (int ch = 0; ch < 4; ch++)
        MFMA_CH(&xarena[0][0], 264, ch*64, Wt2, H, ch*64);
    float bb[4];
    #pragma unroll
    for (int n=0;n<4;n++) bb[n] = b2b[c0 + n*16 + lr];
    __syncthreads();
    #pragma unroll
    for (int rb=0;rb<4;rb++)
        #pragma unroll
        for (int j=0;j<4;j++){
            const int row = rb*16 + lh*4 + j;
            #pragma unroll
            for (int n=0;n<4;n++)
                xarena[row][c0 + n*16 + lr] = f2bf(fmaxf(acc[rb][n][j] + bb[n], 0.f));
        }
    __syncthreads();

    // ---- layer3: K=256, 16 padded cols (4 heads); all waves compute, wave0 writes
    floatx4 a3[4];
    #pragma unroll
    for (int rb=0;rb<4;rb++) a3[rb] = (floatx4){0.f,0.f,0.f,0.f};
    for (int ch = 0; ch < 4; ch++){
        #pragma unroll
        for (int s=0;s<2;s++){
            short8 bfr = *reinterpret_cast<const short8*>(&W3p[lr*H + ch*64 + s*32 + lh*8]);
            #pragma unroll
            for (int rb=0;rb<4;rb++){
                short8 af = *reinterpret_cast<const short8*>(&xarena[rb*16+lr][ch*64 + s*32 + lh*8]);
                a3[rb] = mfma16(af, bfr, a3[rb]);
            }
        }
    }
    if (w == 0 && lr < NHEADS){
        float bias = b3b[lr];
        #pragma unroll
        for (int rb=0;rb<4;rb++)
            #pragma unroll
            for (int j=0;j<4;j++){
                int ge = e0 + rb*16 + lh*4 + j;
                if (ge < E) logits[(size_t)ge*NHEADS + lr] = (a3[rb][j] + bias) * 0.125f;
            }
    }
}

// ---------------- K2: per-node softmax stats ----------------
__global__ void k_smstats(const float* __restrict__ logits, const int* __restrict__ start,
                          float* __restrict__ mbuf, float* __restrict__ dbuf)
{
    int n = blockIdx.x;
    int s = start[n], e_end = start[n+1];
    int lane = threadIdx.x;
    int i = lane >> 2, hh = lane & 3;
    float mx = -INFINITY;
    for (int b = s + i; b < e_end; b += 16) mx = fmaxf(mx, logits[(size_t)b*NHEADS + hh]);
    #pragma unroll
    for (int off=4; off<64; off<<=1) mx = fmaxf(mx, __shfl_xor(mx, off, 64));
    float sum = 0.f;
    for (int b = s + i; b < e_end; b += 16) sum += expf(logits[(size_t)b*NHEADS + hh] - mx);
    #pragma unroll
    for (int off=4; off<64; off<<=1) sum += __shfl_xor(sum, off, 64);
    if (lane < 4){ mbuf[(size_t)n*NHEADS + hh] = mx; dbuf[(size_t)n*NHEADS + hh] = sum; }
}

// ---------------- K3: value MLP (bf16 MFMA, BM=64) + attend + segmented scatter-add ----------------
__global__ void __launch_bounds__(256,3)
k_wv2(const float* __restrict__ hE,
      const short* __restrict__ Wt1, const float* __restrict__ b1v,
      const short* __restrict__ Wt2, const float* __restrict__ b2v,
      const short* __restrict__ Wt3, const float* __restrict__ b3v,
      const int* __restrict__ center, const float* __restrict__ logits,
      const float* __restrict__ mbuf, const float* __restrict__ dbuf,
      float* __restrict__ pre, int E)
{
    __shared__ short Alds[2][BM][72];
    __shared__ short xarena[BM][264];
    __shared__ int   csh[BM];

    const int tid = threadIdx.x;
    const int lane = tid & 63, w = tid >> 6;
    const int lr = lane & 15, lh = lane >> 4;
    const int e0 = blockIdx.x * BM;
    const int c0 = w * 64;
    const int srow = tid >> 2, skq = tid & 3;
    const int gsrow = (e0 + srow < E) ? (e0 + srow) : (E-1);
    const float* aSrc = hE + (size_t)gsrow * NIN + skq * 16;

    if (tid < BM){ int ge = e0 + tid; csh[tid] = center[ge < E ? ge : E-1]; }

    float4 pf[4];
    #pragma unroll
    for (int q=0;q<4;q++) pf[q] = ld4(aSrc + q*4);
    *reinterpret_cast<short8*>(&Alds[0][srow][skq*16])   = pack8(pf[0], pf[1]);
    *reinterpret_cast<short8*>(&Alds[0][srow][skq*16+8]) = pack8(pf[2], pf[3]);

    floatx4 acc[4][4];
    ZERO_ACC();

    // ---- layer1: K=512
    for (int ch = 0; ch < 8; ch++){
        __syncthreads();
        if (ch < 7){
            #pragma unroll
            for (int q=0;q<4;q++) pf[q] = ld4(aSrc + (ch+1)*64 + q*4);
        }
        MFMA_CH(&Alds[ch&1][0][0], 72, 0, Wt1, NIN, ch*64);
        if (ch < 7){
            *reinterpret_cast<short8*>(&Alds[(ch&1)^1][srow][skq*16])   = pack8(pf[0], pf[1]);
            *reinterpret_cast<short8*>(&Alds[(ch&1)^1][srow][skq*16+8]) = pack8(pf[2], pf[3]);
        }
    }
    {
        float bc[4];
        #pragma unroll
        for (int n=0;n<4;n++) bc[n] = b1v[c0 + n*16 + lr];
        #pragma unroll
        for (int rb=0;rb<4;rb++)
            #pragma unroll
            for (int j=0;j<4;j++){
                const int row = rb*16 + lh*4 + j;
                #pragma unroll
                for (int n=0;n<4;n++)
                    xarena[row][c0 + n*16 + lr] = f2bf(gelu_fast(acc[rb][n][j] + bc[n]));
            }
    }
    __syncthreads();

    // ---- layer2: K=256
    ZERO_ACC();
    for (int ch = 0; ch < 4; ch++)
        MFMA_CH(&xarena[0][0], 264, ch*64, Wt2, H, ch*64);
    float bc2[4];
    #pragma unroll
    for (int n=0;n<4;n++) bc2[n] = b2v[c0 + n*16 + lr];
    __syncthreads();
    #pragma unroll
    for (int rb=0;rb<4;rb++)
        #pragma unroll
        for (int j=0;j<4;j++){
            const int row = rb*16 + lh*4 + j;
            #pragma unroll
            for (int n=0;n<4;n++)
                xarena[row][c0 + n*16 + lr] = f2bf(gelu_fast(acc[rb][n][j] + bc2[n]));
        }
    __syncthreads();

    // ---- layer3: K=256 (no activation)
    ZERO_ACC();
    for (int ch = 0; ch < 4; ch++)
        MFMA_CH(&xarena[0][0], 264, ch*64, Wt3, H, ch*64);
    float bc3[4];
    #pragma unroll
    for (int n=0;n<4;n++) bc3[n] = b3v[c0 + n*16 + lr];
    __syncthreads();   // all xarena reads done

    // ---- epilogue: attend (head == wave), store scaled bf16, segmented column reduce
    #pragma unroll
    for (int rb=0;rb<4;rb++)
        #pragma unroll
        for (int j=0;j<4;j++){
            const int row = rb*16 + lh*4 + j;
            const int ge = e0 + row;
            float att = 0.f;
            if (ge < E){
                const int c = csh[row];
                att = fexp2((logits[(size_t)ge*NHEADS + w] - mbuf[(size_t)c*NHEADS + w]) * LOG2E)
                      * frcp(dbuf[(size_t)c*NHEADS + w]);
            }
            #pragma unroll
            for (int n=0;n<4;n++)
                xarena[row][c0 + n*16 + lr] = f2bf((acc[rb][n][j] + bc3[n]) * att);
        }
    __syncthreads();
    {
        const int col = tid;
        float s = 0.f; int cur = csh[0];
        for (int e=0;e<BM;e++){
            int c = csh[e];
            if (c != cur){ atomicAdd(&pre[(size_t)cur*H + col], s); s = 0.f; cur = c; }
            s += bf2f(xarena[e][col]);
        }
        atomicAdd(&pre[(size_t)cur*H + col], s);
    }
}

// ---------------- K4: out = pre @ wo (f32) ----------------
__global__ void __launch_bounds__(256)
k_out(const float* __restrict__ pre, const float* __restrict__ wo,
      float* __restrict__ out, int N)
{
    __shared__ float ps[8][260];
    const int tid = threadIdx.x;
    const int nb = blockIdx.x * 8;
    {
        int r = tid >> 5, c = (tid & 31) * 8;
        *reinterpret_cast<float4*>(&ps[r][c])   = ld4(&pre[(size_t)(nb+r)*H + c]);
        *reinterpret_cast<float4*>(&ps[r][c+4]) = ld4(&pre[(size_t)(nb+r)*H + c+4]);
    }
    __syncthreads();
    float a[8];
    #pragma unroll
    for (int i=0;i<8;i++) a[i]=0.f;
    #pragma unroll 4
    for (int k=0;k<H;k++){
        float w = wo[(size_t)k*H + tid];
        #pragma unroll
        for (int i=0;i<8;i++) a[i] = fmaf(ps[i][k], w, a[i]);
    }
    #pragma unroll
    for (int i=0;i<8;i++)
        out[(size_t)(nb+i)*H + tid] = a[i];
}

extern "C" void kernel_launch(void* const* d_in, const int* in_sizes, int n_in,
                              void* d_out, int out_size, void* d_ws, size_t ws_size,
                              hipStream_t stream)
{
    const float* hV   = (const float*)d_in[0];
    const float* hE   = (const float*)d_in[1];
    const float* wv1w = (const float*)d_in[2];
    const float* wv1b = (const float*)d_in[3];
    const float* wv2w = (const float*)d_in[4];
    const float* wv2b = (const float*)d_in[5];
    const float* wv3w = (const float*)d_in[6];
    const float* wv3b = (const float*)d_in[7];
    const float* b1w  = (const float*)d_in[8];
    const float* b1b  = (const float*)d_in[9];
    const float* b2w  = (const float*)d_in[10];
    const float* b2b  = (const float*)d_in[11];
    const float* b3w  = (const float*)d_in[12];
    const float* b3b  = (const float*)d_in[13];
    const float* wow  = (const float*)d_in[14];
    const int*   center = (const int*)d_in[15];

    const int E = in_sizes[15];
    const int N = in_sizes[0] / H;
    const int nblk = (E + BM - 1) / BM;

    float* pre      = (float*)d_ws;                       // N*H
    float* logits   = pre + (size_t)N*H;                  // E*4
    float* mbuf     = logits + (size_t)E*NHEADS;          // N*4
    float* dbuf     = mbuf + (size_t)N*NHEADS;            // N*4
    int*   start    = (int*)(dbuf + (size_t)N*NHEADS);    // N+1 (padded)
    float* nodebias = (float*)(start + ((N+1+3)&~3));     // N*H
    short* wt1b     = (short*)(nodebias + (size_t)N*H);   // 256*512
    short* wt2b     = wt1b + 256*512;                     // 256*256
    short* w3pb     = wt2b + 256*256;                     // 16*256
    short* wt1v     = w3pb + 16*256;                      // 256*512
    short* wt2v     = wt1v + 256*512;                     // 256*256
    short* wt3v     = wt2v + 256*256;                     // 256*256

    hipMemsetAsync(pre, 0, (size_t)N*H*sizeof(float), stream);
    k_ranges<<<(N+1+255)/256, 256, 0, stream>>>(center, start, E, N);
    k_wconv<<<dim3(16,8), 256, 0, stream>>>(b1w + 256*H, wt1b, 512);
    k_wconv<<<dim3(8,8),  256, 0, stream>>>(b2w,  wt2b, 256);
    k_w3pad<<<1, 256, 0, stream>>>(b3w, w3pb);
    k_wconv<<<dim3(16,8), 256, 0, stream>>>(wv1w, wt1v, 512);
    k_wconv<<<dim3(8,8),  256, 0, stream>>>(wv2w, wt2v, 256);
    k_wconv<<<dim3(8,8),  256, 0, stream>>>(wv3w, wt3v, 256);
    k_nodebias<<<N/8, 256, 0, stream>>>(hV, b1w, b1b, nodebias, N);
    k_bias2<<<nblk, 256, 0, stream>>>(hE, wt1b, wt2b, w3pb, b3b, b2b, nodebias, center, logits, E);
    k_smstats<<<N, 64, 0, stream>>>(logits, start, mbuf, dbuf);
    k_wv2<<<nblk, 256, 0, stream>>>(hE, wt1v, wv1b, wt2v, wv2b, wt3v, wv3b,
                                    center, logits, mbuf, dbuf, pre, E);
    k_out<<<N/8, 256, 0, stream>>>(pre, wow, (float*)d_out, N);
}